// Round 2
// baseline (185.125 us; speedup 1.0000x reference)
//
#include <hip/hip_runtime.h>
#include <math.h>

// Problem constants (from reference)
#define A_ 3
#define H_ 128
#define W_ 128
#define C_ 2
#define ATTRS 7
#define B_ 64
#define CELLS_PER_BATCH (A_*H_*W_)          // 49152
#define TOTAL_CELLS (B_*CELLS_PER_BATCH)    // 3145728

#define NBLK 1536
#define NTHR 256
#define CELLS_PER_BLK (TOTAL_CELLS/NBLK)        // 2048 (contiguous per block)
#define BLKS_PER_BATCH (CELLS_PER_BATCH/CELLS_PER_BLK)  // 24 -> b = blockIdx/24 exact
#define ITERS (CELLS_PER_BLK/NTHR)              // 8
#define NSLOTS 32

// ws float layout:
//   [0..192)    partial sums, index = m*NSLOTS + slot   (m in [0,6))
//   [200]       completion counter (uint bits)
//   [256..1280) per-batch data: 16 floats/batch =
//               t0:[cx,cy,bw,bh][areaT,t5,codef,0]  t1: same
#define WS_CNT   200
#define WS_BATCH 256

__global__ __launch_bounds__(256) void prep_k(
    const float* __restrict__ boxes,
    const int*   __restrict__ labels,
    const float* __restrict__ areas,
    float* __restrict__ ws)
{
    const int tid = threadIdx.x;
    ws[tid] = 0.0f;                 // zero slots [0..192) and counter [200]
    if (tid < B_) {
        const int b = tid;
        float o16[16];
        #pragma unroll
        for (int t = 0; t < 2; ++t) {
            const float x1 = boxes[b*8 + t*4 + 0];
            const float y1 = boxes[b*8 + t*4 + 1];
            const float x2 = boxes[b*8 + t*4 + 2];
            const float y2 = boxes[b*8 + t*4 + 3];
            const float cx = (x1 + x2) * 0.5f, cy = (y1 + y2) * 0.5f;
            const float bw = x2 - x1,          bh = y2 - y1;
            const float at = (bw - cx) * (bh - cy);   // reference "area_t" quirk
            const float ar = areas[b*2 + t];
            const float d0 = fabsf(10440.f - ar);
            const float d1 = fabsf(30888.f - ar);
            const float d2 = fabsf(121598.f - ar);
            int ba = 0; float bd = d0;
            if (d1 < bd) { ba = 1; bd = d1; }
            if (d2 < bd) { ba = 2; }
            const int cX = (int)((bw - cx) * 0.125f); // trunc; always in [0,127] here
            const int cY = (int)((bh - cy) * 0.125f);
            const int code = ba * (H_*W_) + cX * W_ + cY;   // flattened (a,i,j)
            const int lab = labels[b*2 + t];
            const float t5 = (t == 0) ? (lab == 1 ? 1.f : 0.f)
                                      : (lab == 2 ? 1.f : 0.f);
            o16[t*8+0]=cx; o16[t*8+1]=cy; o16[t*8+2]=bw; o16[t*8+3]=bh;
            o16[t*8+4]=at; o16[t*8+5]=t5; o16[t*8+6]=(float)code; o16[t*8+7]=0.f;
        }
        #pragma unroll
        for (int k = 0; k < 16; ++k) ws[WS_BATCH + b*16 + k] = o16[k];
    }
}

__global__ __launch_bounds__(NTHR) void yolo_main_k(
    const float* __restrict__ outp,
    float* __restrict__ ws,
    float* __restrict__ o)
{
    __shared__ float4 s_tile[448];      // 256 cells * 7 floats
    __shared__ float  s_red[4][6];
    __shared__ int    s_last;
    __shared__ float  s_out[6];
    const int tid = threadIdx.x;

    // block-constant batch data (4x float4 from ws, L2-hit)
    const int b       = blockIdx.x / BLKS_PER_BATCH;
    const int colBase = (blockIdx.x % BLKS_PER_BATCH) * CELLS_PER_BLK;
    const float4* wsb = (const float4*)(ws + WS_BATCH) + b*4;
    const float4 p0 = wsb[0], q0 = wsb[1];   // t0
    const float4 p1 = wsb[2], q1 = wsb[3];   // t1
    const int code0 = (int)q0.z, code1 = (int)q1.z;

    float accX = 0.f, accY = 0.f, accW = 0.f, accH = 0.f, accC = 0.f, accK = 0.f;

    for (int it = 0; it < ITERS; ++it) {
        const int base = blockIdx.x * CELLS_PER_BLK + it * NTHR;
        if (it) __syncthreads();
        const float4* gp = (const float4*)(outp + (size_t)base * ATTRS);
        s_tile[tid] = gp[tid];
        if (tid < 192) s_tile[tid + 256] = gp[tid + 256];
        __syncthreads();

        const int r = colBase + it * NTHR + tid;   // within-batch flat (a,i,j)
        const int i = (r >> 7) & 127;
        const int j = r & 127;
        const float* sp = ((const float*)s_tile) + tid * ATTRS; // stride-7: 2-way alias (free)
        const float xr = sp[0], yr = sp[1], w = sp[2], h = sp[3];
        const float conf = sp[4], c0 = sp[5], c1 = sp[6];

        const float fi = (float)i, fj = (float)j;
        const float x = xr - fi, y = yr - fj;
        const float hw = 0.5f * w, hh = 0.5f * h;
        const float px1 = x - hw, px2 = x + hw;
        const float py1 = y - hh, py2 = y + hh;
        const float areaP = (px2 - px1) * (py2 - py1);

        // reference quirk: (tx1,ty1,tx2,ty2) = (cx,cy,bw,bh)
        const float ix0 = fmaxf(fminf(px2, p0.z) - fmaxf(px1, p0.x), 0.f);
        const float iy0 = fmaxf(fminf(py2, p0.w) - fmaxf(py1, p0.y), 0.f);
        const float in0 = ix0 * iy0;
        const float iou0 = in0 / (areaP + q0.x - in0 + 1e-16f);
        const float ix1 = fmaxf(fminf(px2, p1.z) - fmaxf(px1, p1.x), 0.f);
        const float iy1 = fmaxf(fminf(py2, p1.w) - fmaxf(py1, p1.y), 0.f);
        const float in1 = ix1 * iy1;
        const float iou1 = in1 / (areaP + q1.x - in1 + 1e-16f);

        const bool e0 = (r == code0), e1 = (r == code1);
        const bool exact = e0 || e1;
        const bool suppress = (!exact) && (fmaxf(iou0, iou1) > 0.5f);

        if (exact) {                       // <= 2 cells per batch
            // t=1 overwrites t=0 (.at[].set loop order)
            const float cx = e1 ? p1.x : p0.x, cy = e1 ? p1.y : p0.y;
            const float bw = e1 ? p1.z : p0.z, bh = e1 ? p1.w : p0.w;
            const float t5 = e1 ? q1.y : q0.y;
            const float dx = x - (cx - fi); accX += dx * dx;
            const float dy = y - (cy - fj); accY += dy * dy;
            const float dw = w - bw;        accW += dw * dw;
            const float dh = h - bh;        accH += dh * dh;
            accC += fmaxf(logf(conf), -100.f);          // tConf=1
            if (t5 != 0.f)                              // both cls channels get t5
                accK += fmaxf(logf(c0), -100.f) + fmaxf(logf(c1), -100.f);
            else
                accK += fmaxf(log1pf(-c0), -100.f) + fmaxf(log1pf(-c1), -100.f);
        } else if (!suppress) {
            accC += fmaxf(log1pf(-conf), -100.f);       // tConf=0
        }
    }

    // ---- reduction: wave shuffle -> LDS -> 32-slot scatter atomics ----
    float v[6] = {accX, accY, accW, accH, accC, accK};
    #pragma unroll
    for (int m = 0; m < 6; ++m) {
        float s = v[m];
        #pragma unroll
        for (int off = 32; off > 0; off >>= 1) s += __shfl_down(s, off, 64);
        v[m] = s;
    }
    const int wid = tid >> 6;
    if ((tid & 63) == 0) {
        #pragma unroll
        for (int m = 0; m < 6; ++m) s_red[wid][m] = v[m];
    }
    __syncthreads();
    if (tid < 6) {
        const float s = s_red[0][tid] + s_red[1][tid] + s_red[2][tid] + s_red[3][tid];
        atomicAdd(&ws[tid * NSLOTS + (blockIdx.x & (NSLOTS - 1))], s);
    }

    // ---- last block finalizes (device-scope atomics only: XCD-safe) ----
    if (tid == 0) {
        __threadfence();
        const unsigned old = atomicAdd((unsigned*)(ws + WS_CNT), 1u);
        s_last = (old == NBLK - 1u);
    }
    __syncthreads();
    if (!s_last) return;

    float s = (tid < 6 * NSLOTS) ? atomicAdd(&ws[tid], 0.0f) : 0.f;  // coherent read
    #pragma unroll
    for (int off = 16; off > 0; off >>= 1) s += __shfl_xor(s, off, 64); // stays in 32-group
    if (tid < 6 * NSLOTS && (tid & 31) == 0) s_out[tid >> 5] = s;
    __syncthreads();
    if (tid == 0) {
        const float N = (float)TOTAL_CELLS;
        const float xL = s_out[0] / N, yL = s_out[1] / N;
        const float wL = s_out[2] / N, hL = s_out[3] / N;
        const float confL = -s_out[4] / N;
        const float clsL  = -s_out[5] / (N * (float)C_);
        o[0] = 2.5f * (xL + yL) + 2.5f * (wL + hL) + confL + clsL;
        o[1] = xL; o[2] = yL; o[3] = wL; o[4] = hL; o[5] = confL; o[6] = clsL;
    }
}

extern "C" void kernel_launch(void* const* d_in, const int* in_sizes, int n_in,
                              void* d_out, int out_size, void* d_ws, size_t ws_size,
                              hipStream_t stream) {
    const float* outp   = (const float*)d_in[0];
    const float* boxes  = (const float*)d_in[1];
    const int*   labels = (const int*)d_in[2];
    const float* areas  = (const float*)d_in[3];
    float* ws = (float*)d_ws;
    float* o  = (float*)d_out;

    prep_k<<<1, NTHR, 0, stream>>>(boxes, labels, areas, ws);
    yolo_main_k<<<NBLK, NTHR, 0, stream>>>(outp, ws, o);
}